// Round 15
// baseline (211.807 us; speedup 1.0000x reference)
//
#include <hip/hip_runtime.h>
#include <hip/hip_bf16.h>
#include <math.h>

typedef _Float16 f16x8 __attribute__((ext_vector_type(8)));
typedef float f32x4 __attribute__((ext_vector_type(4)));
typedef float f32x2 __attribute__((ext_vector_type(2)));
typedef unsigned short u16;
typedef unsigned int u32;
typedef u16 u16x4 __attribute__((ext_vector_type(4)));
typedef u16 u16x8 __attribute__((ext_vector_type(8)));

#define DEVI static __device__ __forceinline__
#define LDSS 72  // attn LDS row stride (16B-aligned pad)
#define MB (1u << 20)

DEVI u16 f2h(float f) {
    _Float16 h = (_Float16)f;
    return __builtin_bit_cast(u16, h);
}
DEVI float h2f(u16 u) {
    return (float)__builtin_bit_cast(_Float16, u);
}
DEVI f32x4 mfma16(f16x8 a, f16x8 b, f32x4 c) {
    return __builtin_amdgcn_mfma_f32_16x16x32_f16(a, b, c, 0, 0, 0);
}
DEVI void gload16(const u16* g, u16* l) {
    __builtin_amdgcn_global_load_lds((const __attribute__((address_space(1))) void*)g,
                                     (__attribute__((address_space(3))) void*)l, 16, 0, 0);
}

// stage a 128x64 f16 tile global -> LDS (linear [128][64]) via global_load_lds.
DEVI void stage128(const u16* __restrict__ g, size_t row0, int ldg, int k0, u16* lds) {
    int t = threadIdx.x;
    const u16* src = g + (row0 + (size_t)(t >> 3)) * (size_t)ldg + k0 + (t & 7) * 8;
    u16* dst = lds + (t >> 6) * 512;  // wave-uniform
#pragma unroll
    for (int is = 0; is < 4; is++)
        gload16(src + (size_t)is * 32 * ldg, dst + is * 2048);
}

// ---------------- 128x128 MFMA core: C[m,n] = sum_k A[m,k]*B[n,k], f16 in ----------------
DEVI void gemm128_core(const u16* __restrict__ A, const u16* __restrict__ B,
                       int ldk, int kbeg, int kend, int m0, int n0,
                       u16* As, u16* Bs, f32x4 acc[4][4]) {
    int lane = threadIdx.x & 63, w = threadIdx.x >> 6;
    int wm = (w >> 1) * 64, wn = (w & 1) * 64;
    int lrow = lane & 15, lg = lane >> 4;
    for (int k0 = kbeg; k0 < kend; k0 += 64) {
        __syncthreads();
        stage128(A, m0, ldk, k0, As);
        stage128(B, n0, ldk, k0, Bs);
        __syncthreads();
#pragma unroll
        for (int ks = 0; ks < 2; ks++) {
            f16x8 af[4], bf[4];
#pragma unroll
            for (int i = 0; i < 4; i++) {
                af[i] = *reinterpret_cast<f16x8*>(&As[(wm + i * 16 + lrow) * 64 + ks * 32 + lg * 8]);
                bf[i] = *reinterpret_cast<f16x8*>(&Bs[(wn + i * 16 + lrow) * 64 + ks * 32 + lg * 8]);
            }
#pragma unroll
            for (int i = 0; i < 4; i++)
#pragma unroll
                for (int j = 0; j < 4; j++)
                    acc[i][j] = mfma16(af[i], bf[j], acc[i][j]);
        }
    }
}

// ---------------- fp32 -> f16 one-time conversion; Wfc u/v rows interleaved ----------------
__global__ void cvt_kernel(const float* __restrict__ h, const float* __restrict__ Wq,
                           const float* __restrict__ Wk, const float* __restrict__ Wv,
                           const float* __restrict__ Wo, const float* __restrict__ Wfc,
                           const float* __restrict__ Wproj, u16* __restrict__ dst) {
    int bid = blockIdx.x;
    const float* src;
    size_t doff;
    int sb;
    bool ilv = false;
    if (bid < 1024)      { src = h;     sb = 0;    doff = 0; }
    else if (bid < 1536) { src = Wq;    sb = 1024; doff = 2097152; }
    else if (bid < 2048) { src = Wk;    sb = 1536; doff = 3145728; }
    else if (bid < 2560) { src = Wv;    sb = 2048; doff = 4194304; }
    else if (bid < 3072) { src = Wo;    sb = 2560; doff = 5242880; }
    else if (bid < 7168) { src = Wfc;   sb = 3072; doff = 10485760; ilv = true; }
    else                 { src = Wproj; sb = 7168; doff = 6291456; }
    size_t idx = (size_t)(bid - sb) * 2048 + threadIdx.x * 8;
    f32x4 a = *reinterpret_cast<const f32x4*>(src + idx);
    f32x4 b = *reinterpret_cast<const f32x4*>(src + idx + 4);
    u16x8 o;
    o[0] = f2h(a[0]); o[1] = f2h(a[1]); o[2] = f2h(a[2]); o[3] = f2h(a[3]);
    o[4] = f2h(b[0]); o[5] = f2h(b[1]); o[6] = f2h(b[2]); o[7] = f2h(b[3]);
    size_t didx = idx;
    if (ilv) {  // Wfc2: row 2n = u_n (src row n), row 2n+1 = v_n (src row 4096+n)
        size_t row = idx >> 10, col = idx & 1023;
        size_t nrow = (row < 4096) ? (row * 2) : ((row - 4096) * 2 + 1);
        didx = nrow * 1024 + col;
    }
    *reinterpret_cast<u16x8*>(dst + doff + didx) = o;
}

// ---------------- QKV ----------------
__global__ __launch_bounds__(256, 2) void qkv_h_kernel(
    const u16* __restrict__ hb, const u16* __restrict__ Wqh, const u16* __restrict__ Wkh,
    const u16* __restrict__ Wvh, u16* __restrict__ qb, u16* __restrict__ kb, u16* __restrict__ vb) {
    __shared__ u16 As[128 * 64];
    __shared__ u16 Bs[128 * 64];
    int z = blockIdx.z;
    const u16* W = (z == 0) ? Wqh : (z == 1) ? Wkh : Wvh;
    u16* dst = (z == 0) ? qb : (z == 1) ? kb : vb;
    int m0 = blockIdx.y * 128, n0 = blockIdx.x * 128;
    f32x4 acc[4][4];
    f32x4 zf = {0.f, 0.f, 0.f, 0.f};
#pragma unroll
    for (int i = 0; i < 4; i++)
#pragma unroll
        for (int j = 0; j < 4; j++) acc[i][j] = zf;
    gemm128_core(hb, W, 1024, 0, 1024, m0, n0, As, Bs, acc);
    int lane = threadIdx.x & 63, w = threadIdx.x >> 6;
    int wm = (w >> 1) * 64, wn = (w & 1) * 64;
    int lrow = lane & 15, lg = lane >> 4;
#pragma unroll
    for (int i = 0; i < 4; i++)
#pragma unroll
        for (int j = 0; j < 4; j++)
#pragma unroll
            for (int r = 0; r < 4; r++) {
                int m = m0 + wm + i * 16 + lg * 4 + r;
                int n = n0 + wn + j * 16 + lrow;
                dst[(size_t)m * 1024 + n] = f2h(acc[i][j][r]);
            }
}

// ---------------- generic 128x128 GEMM, f16 out, optional K-split via grid.z ----------------
__global__ __launch_bounds__(256, 2) void gemm_h_kernel(
    const u16* __restrict__ A, const u16* __restrict__ B, u16* __restrict__ out,
    int ldk, int ksplit, int osplit, int N) {
    __shared__ u16 As[128 * 64];
    __shared__ u16 Bs[128 * 64];
    int z = blockIdx.z;
    int m0 = blockIdx.y * 128, n0 = blockIdx.x * 128;
    f32x4 acc[4][4];
    f32x4 zf = {0.f, 0.f, 0.f, 0.f};
#pragma unroll
    for (int i = 0; i < 4; i++)
#pragma unroll
        for (int j = 0; j < 4; j++) acc[i][j] = zf;
    gemm128_core(A, B, ldk, z * ksplit, (z + 1) * ksplit, m0, n0, As, Bs, acc);
    u16* o = out + (size_t)z * osplit;
    int lane = threadIdx.x & 63, w = threadIdx.x >> 6;
    int wm = (w >> 1) * 64, wn = (w & 1) * 64;
    int lrow = lane & 15, lg = lane >> 4;
#pragma unroll
    for (int i = 0; i < 4; i++)
#pragma unroll
        for (int j = 0; j < 4; j++)
#pragma unroll
            for (int r = 0; r < 4; r++) {
                int m = m0 + wm + i * 16 + lg * 4 + r;
                int n = n0 + wn + j * 16 + lrow;
                o[(size_t)m * N + n] = f2h(acc[i][j][r]);
            }
}

// ---------------- RoPE + L2 norm + sqk scale, f16 in-place ----------------
__global__ void qkprep_kernel(u16* __restrict__ qb, u16* __restrict__ kb,
                              const float* __restrict__ sqk) {
    u16* buf = blockIdx.z ? kb : qb;
    int pair = blockIdx.x * 4 + (threadIdx.x >> 6);  // (m,h) pair
    int m = pair >> 4, hh = pair & 15;
    int tt = m & 1023;  // t = m % T
    int d = threadIdx.x & 63;
    size_t off = (size_t)m * 1024 + hh * 64 + d;
    float x = h2f(buf[off]);
    float xn = __shfl_xor(x, 1);
    int j = (d & 1) ? ((d - 1) >> 1) : (32 + (d >> 1));
    float dv = exp2f(-(float)(j >> 1) * 0.41524101186092029f);  // log2(10000)/32
    float ang = (float)tt * dv;
    float e = (j & 1) ? cosf(ang) : sinf(ang);
    float xr = (d & 1) ? (xn * e) : (-xn * e);
    float ss = xr * xr;
#pragma unroll
    for (int o = 1; o < 64; o <<= 1) ss += __shfl_xor(ss, o);
    float sc = rsqrtf(ss) * sqk[hh * 64 + d] * 32.0f;
    buf[off] = f2h(xr * sc);
}

// ---------------- flash attention, split-KV x4, SHARED-KV 4-wave blocks ----------------
__global__ __launch_bounds__(256) void attn_kernel(
    const u16* __restrict__ qb, const u16* __restrict__ kb, const u16* __restrict__ vb,
    const float* __restrict__ thr_c, const float* __restrict__ stp,
    u16* __restrict__ yph, f32x2* __restrict__ mden) {
    const int T = 1024, C = 1024;
    int p = 15 - (blockIdx.x >> 2);   // heavy-first, q-rows [64p, 64p+64)
    int c = blockIdx.x & 3;           // kv chunk (stride-4 tiles)
    int bh = blockIdx.y;
    int b = bh >> 4, hh = bh & 15;
    int nkt = p + 1;                  // wave-uniform
    __shared__ u16 Vt[2][64 * LDSS];  // double-buffered transposed V (shared by 4 waves)
    __shared__ u16 Ps[64 * LDSS];     // P rows, wave-private 16-row slices
    int t = threadIdx.x;
    int lane = t & 63, w = t >> 6;    // wave 0..3
    int lrow = lane & 15, lg = lane >> 4, lk = lg * 8;
    int kvp = t & 31, db = t >> 5;    // V-stage: 2 kv rows x 8 d per thread

    int qrow0 = 64 * p + 16 * w;      // this wave's 16 q-rows
    const u16* qrowp = qb + (size_t)(b * T + qrow0 + lrow) * C + hh * 64;
    f16x8 qfr[2];
    qfr[0] = *reinterpret_cast<const f16x8*>(qrowp + lk);
    qfr[1] = *reinterpret_cast<const f16x8*>(qrowp + 32 + lk);

    float thr = thr_c[hh], st = stp[hh];
    float stthr = st * thr;
    float mrun = -1e30f, den = 0.f;
    f32x4 yacc[4];
    f32x4 zf = {0.f, 0.f, 0.f, 0.f};
#pragma unroll
    for (int i = 0; i < 4; i++) yacc[i] = zf;
    int qg = qrow0 + lrow;

    f16x8 kpre[8];   // prefetched K fragments
    u16x4 vr[4];     // prefetched V: 2 kv rows x 8 d per thread
    const u16* kbase0 = kb + (size_t)(b * T + lrow) * C + hh * 64 + lk;
    const u16* vbase0 = vb + (size_t)(b * T + 2 * kvp) * C + hh * 64 + db * 8;

    if (c < nkt) {  // prologue prefetch of tile c
        const u16* kbase = kbase0 + (size_t)(c << 6) * C;
        const u16* vsrc = vbase0 + (size_t)(c << 6) * C;
#pragma unroll
        for (int ks = 0; ks < 2; ks++)
#pragma unroll
            for (int f = 0; f < 4; f++)
                kpre[ks * 4 + f] = *reinterpret_cast<const f16x8*>(kbase + (size_t)(f * 16) * C + ks * 32);
        vr[0] = *reinterpret_cast<const u16x4*>(vsrc);
        vr[1] = *reinterpret_cast<const u16x4*>(vsrc + 4);
        vr[2] = *reinterpret_cast<const u16x4*>(vsrc + C);
        vr[3] = *reinterpret_cast<const u16x4*>(vsrc + C + 4);
    }

    int bufsel = 0;
    for (int kt = c; kt < nkt; kt += 4) {
        int kv0 = kt << 6;
        u16* VB = Vt[bufsel];
        bufsel ^= 1;
#pragma unroll
        for (int dd = 0; dd < 2; dd++)
#pragma unroll
            for (int e = 0; e < 4; e++) {
                u32 v = (u32)vr[dd][e] | ((u32)vr[2 + dd][e] << 16);
                *reinterpret_cast<u32*>(&VB[(db * 8 + dd * 4 + e) * LDSS + 2 * kvp]) = v;
            }
        f32x4 sacc[4];
#pragma unroll
        for (int f = 0; f < 4; f++) sacc[f] = zf;
        __builtin_amdgcn_s_setprio(1);
#pragma unroll
        for (int ks = 0; ks < 2; ks++)
#pragma unroll
            for (int f = 0; f < 4; f++)
                sacc[f] = mfma16(kpre[ks * 4 + f], qfr[ks], sacc[f]);
        __builtin_amdgcn_s_setprio(0);

        if (kt + 4 < nkt) {
            const u16* kbase = kbase0 + (size_t)((kt + 4) << 6) * C;
            const u16* vsrc = vbase0 + (size_t)((kt + 4) << 6) * C;
#pragma unroll
            for (int ks = 0; ks < 2; ks++)
#pragma unroll
                for (int f = 0; f < 4; f++)
                    kpre[ks * 4 + f] = *reinterpret_cast<const f16x8*>(kbase + (size_t)(f * 16) * C + ks * 32);
            vr[0] = *reinterpret_cast<const u16x4*>(vsrc);
            vr[1] = *reinterpret_cast<const u16x4*>(vsrc + 4);
            vr[2] = *reinterpret_cast<const u16x4*>(vsrc + C);
            vr[3] = *reinterpret_cast<const u16x4*>(vsrc + C + 4);
        }

        float svv[16];
        float tmax = -1e30f;
        bool last = (kt == nkt - 1);
#pragma unroll
        for (int f = 0; f < 4; f++)
#pragma unroll
            for (int r = 0; r < 4; r++) {
                float s = sacc[f][r] * 8.0f;  // * sqrt(D)
                if (last) {
                    int kvg = kv0 + f * 16 + lg * 4 + r;
                    if (kvg > qg) s = -1e30f;
                }
                svv[f * 4 + r] = s;
                tmax = fmaxf(tmax, s);
            }
        tmax = fmaxf(tmax, __shfl_xor(tmax, 16));
        tmax = fmaxf(tmax, __shfl_xor(tmax, 32));
        float zM = stthr - st * tmax;
        float spM = tmax - __logf(1.0f + __expf(zM));
        float mnew = fmaxf(mrun, spM);
        float alpha = __expf(mrun - mnew);
        float tden = 0.f;
        u16 pu[16];
#pragma unroll
        for (int i = 0; i < 16; i++) {
            float s = svv[i];
            float e2 = __expf(s - mnew);
            float eg = __expf(stthr - st * s);
            float pp = e2 * __builtin_amdgcn_rcpf(1.0f + eg);
            u16 ph = f2h(pp);
            pu[i] = ph;
            tden += h2f(ph);  // denominator from quantized P: rounding cancels
        }
        tden += __shfl_xor(tden, 16);
        tden += __shfl_xor(tden, 32);
        den = den * alpha + tden;
        mrun = mnew;

#pragma unroll
        for (int f = 0; f < 4; f++) {
            u16x4 u = {pu[f * 4 + 0], pu[f * 4 + 1], pu[f * 4 + 2], pu[f * 4 + 3]};
            *reinterpret_cast<u16x4*>(&Ps[(w * 16 + lrow) * LDSS + f * 16 + lg * 4]) = u;
        }
        float a4[4];
#pragma unroll
        for (int r = 0; r < 4; r++) a4[r] = __shfl(alpha, lg * 4 + r);
#pragma unroll
        for (int nf = 0; nf < 4; nf++)
#pragma unroll
            for (int r = 0; r < 4; r++) yacc[nf][r] *= a4[r];

        __syncthreads();  // VB staged by all waves; single barrier per tile (dbuf = WAR-safe)

        __builtin_amdgcn_s_setprio(1);
#pragma unroll
        for (int ks = 0; ks < 2; ks++) {
            f16x8 pf = *reinterpret_cast<f16x8*>(&Ps[(w * 16 + lrow) * LDSS + ks * 32 + lk]);
#pragma unroll
            for (int nf = 0; nf < 4; nf++) {
                f16x8 vf = *reinterpret_cast<f16x8*>(&VB[(nf * 16 + lrow) * LDSS + ks * 32 + lk]);
                yacc[nf] = mfma16(pf, vf, yacc[nf]);
            }
        }
        __builtin_amdgcn_s_setprio(0);
    }
    u16* ypc = yph + (size_t)c * 2097152;
#pragma unroll
    for (int nf = 0; nf < 4; nf++)
#pragma unroll
        for (int r = 0; r < 4; r++) {
            int qrow = qrow0 + lg * 4 + r;
            ypc[(size_t)(b * T + qrow) * C + hh * 64 + nf * 16 + lrow] = f2h(yacc[nf][r]);
        }
    if (lg == 0) {
        f32x2 md;
        md[0] = mrun; md[1] = den;
        mden[((size_t)c * 32 + bh) * 1024 + (qrow0 + lrow)] = md;
    }
}

// ---------------- merge 4 split-KV partials -> normalized f16 y ----------------
__global__ void attn_merge_kernel(const u16* __restrict__ yph, const f32x2* __restrict__ mden,
                                  u16* __restrict__ y) {
    int row = blockIdx.x;  // b*T + t
    int b = row >> 10, tr = row & 1023;
    int t = threadIdx.x;
#pragma unroll
    for (int i = 0; i < 4; i++) {
        int idx = t + 256 * i;
        int hh = idx >> 6;
        float m[4], d[4];
        float M = -1e30f;
#pragma unroll
        for (int p = 0; p < 4; p++) {
            f32x2 md = mden[((size_t)p * 32 + b * 16 + hh) * 1024 + tr];
            m[p] = md[0]; d[p] = md[1];
            M = fmaxf(M, m[p]);
        }
        size_t off = (size_t)row * 1024 + idx;
        float dn = 0.f, acc = 0.f;
#pragma unroll
        for (int p = 0; p < 4; p++) {
            float wp = __expf(m[p] - M);
            dn += d[p] * wp;
            acc += h2f(yph[off + (size_t)p * 2097152]) * wp;
        }
        y[off] = f2h(acc / dn);
    }
}

// ---------------- FC + SiLU, 256x256-interleaved tile, per-wave 128x64, counted-vmcnt dbuf --
// DS-instr-throughput fix: MFMA:ds_read ratio 2.67 (64 MFMA / 24 reads per wave per K-step)
// vs prior 2.0; staging bytes/FLOP -33%; grid 256 blocks = exactly 1/CU (single generation).
// Wfc2 is u/v row-interleaved (row 2q=u_q, 2q+1=v_q); epilogue pairs via shfl_xor(1).
__global__ __launch_bounds__(512, 2) void fc256_kernel(
    const u16* __restrict__ h1h, const u16* __restrict__ Wfc2,
    const float* __restrict__ suv, u16* __restrict__ xmlp) {
    __shared__ u16 L[2][2][16384];  // [slot][A/B][256x64] = 128 KB
    int t = threadIdx.x;
    int lane = t & 63, wid = t >> 6;
    int wm = (wid >> 2) * 128;      // 2 M-groups x 128 rows
    int wn = (wid & 3) * 64;        // 4 N-groups x 64 interleaved cols
    int lrow = lane & 15, lg = lane >> 4;
    int m0 = blockIdx.y * 256;
    int n0 = blockIdx.x * 256;      // interleaved col base

    int sr = t >> 3;                        // base staging row (0..63)
    int sc = ((t & 7) ^ (sr & 7)) * 8;      // pre-swizzled source col (involution)
    int wb = wid * 512;                     // wave-uniform dest base (u16)

    f32x4 acc[8][4];
    f32x4 zf = {0.f, 0.f, 0.f, 0.f};
#pragma unroll
    for (int i = 0; i < 8; i++)
#pragma unroll
        for (int j = 0; j < 4; j++) acc[i][j] = zf;

#define FC_ST(kt, slot) do { \
    int kk_ = (kt) * 64; \
    _Pragma("unroll") \
    for (int l = 0; l < 4; l++) { \
        gload16(h1h + (size_t)(m0 + l * 64 + sr) * 1024 + kk_ + sc, &L[slot][0][l * 4096 + wb]); \
        gload16(Wfc2 + (size_t)(n0 + l * 64 + sr) * 1024 + kk_ + sc, &L[slot][1][l * 4096 + wb]); \
    } } while (0)

    FC_ST(0, 0);
    for (int kt = 0; kt < 16; kt++) {
        int cur = kt & 1;
        if (kt < 15) {
            FC_ST(kt + 1, cur ^ 1);
            asm volatile("s_waitcnt vmcnt(8)" ::: "memory");  // tile kt landed; kt+1 in flight
        } else {
            asm volatile("s_waitcnt vmcnt(0)" ::: "memory");
        }
        __builtin_amdgcn_s_barrier();
        __builtin_amdgcn_sched_barrier(0);
#pragma unroll
        for (int ks = 0; ks < 2; ks++) {
            f16x8 a[8], b[4];
#pragma unroll
            for (int i = 0; i < 8; i++) {
                int r = wm + i * 16 + lrow;
                a[i] = *reinterpret_cast<const f16x8*>(&L[cur][0][r * 64 + ((ks * 4 + lg) ^ (r & 7)) * 8]);
            }
#pragma unroll
            for (int j = 0; j < 4; j++) {
                int r = wn + j * 16 + lrow;
                b[j] = *reinterpret_cast<const f16x8*>(&L[cur][1][r * 64 + ((ks * 4 + lg) ^ (r & 7)) * 8]);
            }
            __builtin_amdgcn_s_setprio(1);
#pragma unroll
            for (int i = 0; i < 8; i++)
#pragma unroll
                for (int j = 0; j < 4; j++)
                    acc[i][j] = mfma16(a[i], b[j], acc[i][j]);
            __builtin_amdgcn_s_setprio(0);
        }
        __builtin_amdgcn_s_barrier();  // reads of slot done before next overwrite
    }
#undef FC_ST
    // epilogue: pair u/v via shfl_xor(1) (even interleaved col = u, odd = v)
#pragma unroll
    for (int i = 0; i < 8; i++)
#pragma unroll
        for (int j = 0; j < 4; j++) {
            int nilv = wn + j * 16 + lrow;
            int q = (n0 + nilv) >> 1;
            bool isu = (nilv & 1) == 0;
            float su = suv[q] * 32.0f;
            float sv = suv[4096 + q] * 32.0f;
#pragma unroll
            for (int r = 0; r < 4; r++) {
                int m = m0 + wm + i * 16 + lg * 4 + r;
                float own = acc[i][j][r];
                float other = __shfl_xor(own, 1);
                float uu = (isu ? own : other) * su;
                float vv = (isu ? other : own) * sv;
                float sig = 1.0f / (1.0f + __expf(-vv));
                if (isu) xmlp[(size_t)m * 4096 + q] = f2h(uu * vv * sig);
            }
        }
}

// ---------------- justnorm residual-lerp-justnorm; delta = sum of f16 parts ----------------
__global__ void normres_kernel(const float* __restrict__ base, const u16* __restrict__ dparts,
                               int nparts, int pstride, const float* __restrict__ alpha,
                               float* __restrict__ outf, u16* __restrict__ outh) {
    int row = blockIdx.x;
    int t = threadIdx.x;
    const float* pb = base + (size_t)row * 1024;
    float xb[4], xd[4];
    float ssb = 0.f, ssd = 0.f;
#pragma unroll
    for (int i = 0; i < 4; i++) {
        size_t off = (size_t)row * 1024 + t + 256 * i;
        xb[i] = pb[t + 256 * i];
        float d = 0.f;
        for (int p = 0; p < nparts; p++) d += h2f(dparts[off + (size_t)p * pstride]);
        xd[i] = d;
        ssb += xb[i] * xb[i];
        ssd += xd[i] * xd[i];
    }
#pragma unroll
    for (int o = 1; o < 64; o <<= 1) { ssb += __shfl_xor(ssb, o); ssd += __shfl_xor(ssd, o); }
    __shared__ float red[8];
    int w = t >> 6;
    if ((t & 63) == 0) { red[w * 2] = ssb; red[w * 2 + 1] = ssd; }
    __syncthreads();
    ssb = red[0] + red[2] + red[4] + red[6];
    ssd = red[1] + red[3] + red[5] + red[7];
    float rb = rsqrtf(ssb), rd = rsqrtf(ssd);
    float c[4];
    float ssc = 0.f;
#pragma unroll
    for (int i = 0; i < 4; i++) {
        float a = xb[i] * rb;
        float bb = xd[i] * rd;
        float lr = fabsf(alpha[t + 256 * i] * 1.6f);  // 0.05/0.03125
        float cv = a + lr * (bb - a);
        c[i] = cv;
        ssc += cv * cv;
    }
#pragma unroll
    for (int o = 1; o < 64; o <<= 1) ssc += __shfl_xor(ssc, o);
    __syncthreads();
    if ((t & 63) == 0) red[w] = ssc;
    __syncthreads();
    ssc = red[0] + red[1] + red[2] + red[3];
    float rc = rsqrtf(ssc);
#pragma unroll
    for (int i = 0; i < 4; i++) {
        float v = c[i] * rc;
        size_t off = (size_t)row * 1024 + t + 256 * i;
        outf[off] = v;
        if (outh) outh[off] = f2h(v);
    }
}

extern "C" void kernel_launch(void* const* d_in, const int* in_sizes, int n_in,
                              void* d_out, int out_size, void* d_ws, size_t ws_size,
                              hipStream_t stream) {
    const float* h = (const float*)d_in[0];
    const float* Wq = (const float*)d_in[1];
    const float* Wk = (const float*)d_in[2];
    const float* Wv = (const float*)d_in[3];
    const float* Wo = (const float*)d_in[4];
    const float* Wfc = (const float*)d_in[5];
    const float* Wproj = (const float*)d_in[6];
    const float* sqk = (const float*)d_in[7];
    const float* suv = (const float*)d_in[8];
    const float* attn_alpha = (const float*)d_in[9];
    const float* mlp_alpha = (const float*)d_in[10];
    const float* thr_c = (const float*)d_in[11];
    const float* stp = (const float*)d_in[12];

    char* ws = (char*)d_ws;
    u16* f16heap = (u16*)ws;
    u16* hb     = f16heap + 0;         // 2048x1024       ( 0..4MB)
    u16* Wqh    = f16heap + 2097152;   // 1024x1024       ( 4..6MB)
    u16* Wkh    = f16heap + 3145728;   //                 ( 6..8MB)
    u16* Wvh    = f16heap + 4194304;   //                 ( 8..10MB)
    u16* Woh    = f16heap + 5242880;   //                 (10..12MB)
    u16* Wprojh = f16heap + 6291456;   // 1024x4096       (12..20MB)
    u16* Wfc2   = f16heap + 10485760;  // 8192x1024 u/v-interleaved (20..36MB)
    u16* partsP = Wfc2;                // proj partials 4x(2048x1024), after Wfc2 dead
    u16* qb   = (u16*)(ws + (size_t)36 * MB);
    u16* kb   = (u16*)(ws + (size_t)40 * MB);
    u16* vb   = (u16*)(ws + (size_t)44 * MB);
    u16* y    = (u16*)(ws + (size_t)48 * MB);     // merged attn out (48..52)
    u16* yph  = (u16*)(ws + (size_t)52 * MB);     // 4 x 4MB f16 attn partials (52..68)
    f32x2* mden = (f32x2*)(ws + (size_t)68 * MB); // 1MB (68..69)
    u16* hattP = (u16*)(ws + (size_t)52 * MB);    // Wo partials 4x4MB (52..68; yph dead post-merge)
    float* h1 = (float*)(ws + (size_t)36 * MB);   // 36..44 (qb/kb dead post-attn)
    u16* h1h  = (u16*)(ws + (size_t)44 * MB);     // 44..48 (vb dead post-attn)
    u16* xmlp = (u16*)(ws + (size_t)52 * MB);     // 52..68 (hattP dead post-normres1)
    float* out = (float*)d_out;

    cvt_kernel<<<9216, 256, 0, stream>>>(h, Wq, Wk, Wv, Wo, Wfc, Wproj, f16heap);
    qkv_h_kernel<<<dim3(8, 16, 3), 256, 0, stream>>>(hb, Wqh, Wkh, Wvh, qb, kb, vb);
    qkprep_kernel<<<dim3(8192, 1, 2), 256, 0, stream>>>(qb, kb, sqk);
    attn_kernel<<<dim3(64, 32), 256, 0, stream>>>(qb, kb, vb, thr_c, stp, yph, mden);
    attn_merge_kernel<<<2048, 256, 0, stream>>>(yph, mden, y);
    gemm_h_kernel<<<dim3(8, 16, 4), 256, 0, stream>>>(y, Woh, hattP, 1024, 256, 2097152, 1024);
    normres_kernel<<<2048, 256, 0, stream>>>(h, hattP, 4, 2097152, attn_alpha, h1, h1h);
    fc256_kernel<<<dim3(32, 8), 512, 0, stream>>>(h1h, Wfc2, suv, xmlp);
    gemm_h_kernel<<<dim3(8, 16, 4), 256, 0, stream>>>(xmlp, Wprojh, partsP, 4096, 1024, 2097152, 1024);
    normres_kernel<<<2048, 256, 0, stream>>>(h1, partsP, 4, 2097152, mlp_alpha, out, (u16*)nullptr);
}

// Round 16
// 203.484 us; speedup vs baseline: 1.0409x; 1.0409x over previous
//
#include <hip/hip_runtime.h>
#include <hip/hip_bf16.h>
#include <math.h>

typedef _Float16 f16x8 __attribute__((ext_vector_type(8)));
typedef float f32x4 __attribute__((ext_vector_type(4)));
typedef float f32x2 __attribute__((ext_vector_type(2)));
typedef unsigned short u16;
typedef unsigned int u32;
typedef u16 u16x4 __attribute__((ext_vector_type(4)));
typedef u16 u16x8 __attribute__((ext_vector_type(8)));

#define DEVI static __device__ __forceinline__
#define LDSS 72  // attn LDS row stride (16B-aligned pad)
#define MB (1u << 20)

DEVI u16 f2h(float f) {
    _Float16 h = (_Float16)f;
    return __builtin_bit_cast(u16, h);
}
DEVI float h2f(u16 u) {
    return (float)__builtin_bit_cast(_Float16, u);
}
DEVI f32x4 mfma16(f16x8 a, f16x8 b, f32x4 c) {
    return __builtin_amdgcn_mfma_f32_16x16x32_f16(a, b, c, 0, 0, 0);
}
DEVI void gload16(const u16* g, u16* l) {
    __builtin_amdgcn_global_load_lds((const __attribute__((address_space(1))) void*)g,
                                     (__attribute__((address_space(3))) void*)l, 16, 0, 0);
}

// stage a 128x64 f16 tile global -> LDS (linear [128][64]) via global_load_lds.
DEVI void stage128(const u16* __restrict__ g, size_t row0, int ldg, int k0, u16* lds) {
    int t = threadIdx.x;
    const u16* src = g + (row0 + (size_t)(t >> 3)) * (size_t)ldg + k0 + (t & 7) * 8;
    u16* dst = lds + (t >> 6) * 512;  // wave-uniform
#pragma unroll
    for (int is = 0; is < 4; is++)
        gload16(src + (size_t)is * 32 * ldg, dst + is * 2048);
}

// ---------------- 128x128 MFMA core: C[m,n] = sum_k A[m,k]*B[n,k], f16 in ----------------
DEVI void gemm128_core(const u16* __restrict__ A, const u16* __restrict__ B,
                       int ldk, int kbeg, int kend, int m0, int n0,
                       u16* As, u16* Bs, f32x4 acc[4][4]) {
    int lane = threadIdx.x & 63, w = threadIdx.x >> 6;
    int wm = (w >> 1) * 64, wn = (w & 1) * 64;
    int lrow = lane & 15, lg = lane >> 4;
    for (int k0 = kbeg; k0 < kend; k0 += 64) {
        __syncthreads();
        stage128(A, m0, ldk, k0, As);
        stage128(B, n0, ldk, k0, Bs);
        __syncthreads();
#pragma unroll
        for (int ks = 0; ks < 2; ks++) {
            f16x8 af[4], bf[4];
#pragma unroll
            for (int i = 0; i < 4; i++) {
                af[i] = *reinterpret_cast<f16x8*>(&As[(wm + i * 16 + lrow) * 64 + ks * 32 + lg * 8]);
                bf[i] = *reinterpret_cast<f16x8*>(&Bs[(wn + i * 16 + lrow) * 64 + ks * 32 + lg * 8]);
            }
#pragma unroll
            for (int i = 0; i < 4; i++)
#pragma unroll
                for (int j = 0; j < 4; j++)
                    acc[i][j] = mfma16(af[i], bf[j], acc[i][j]);
        }
    }
}

// ---------------- fp32 -> f16 one-time conversion of h + all weights ----------------
__global__ void cvt_kernel(const float* __restrict__ h, const float* __restrict__ Wq,
                           const float* __restrict__ Wk, const float* __restrict__ Wv,
                           const float* __restrict__ Wo, const float* __restrict__ Wfc,
                           const float* __restrict__ Wproj, u16* __restrict__ dst) {
    int bid = blockIdx.x;
    const float* src;
    size_t doff;
    int sb;
    if (bid < 1024)      { src = h;     sb = 0;    doff = 0; }
    else if (bid < 1536) { src = Wq;    sb = 1024; doff = 2097152; }
    else if (bid < 2048) { src = Wk;    sb = 1536; doff = 3145728; }
    else if (bid < 2560) { src = Wv;    sb = 2048; doff = 4194304; }
    else if (bid < 3072) { src = Wo;    sb = 2560; doff = 5242880; }
    else if (bid < 7168) { src = Wfc;   sb = 3072; doff = 10485760; }
    else                 { src = Wproj; sb = 7168; doff = 6291456; }
    size_t idx = (size_t)(bid - sb) * 2048 + threadIdx.x * 8;
    f32x4 a = *reinterpret_cast<const f32x4*>(src + idx);
    f32x4 b = *reinterpret_cast<const f32x4*>(src + idx + 4);
    u16x8 o;
    o[0] = f2h(a[0]); o[1] = f2h(a[1]); o[2] = f2h(a[2]); o[3] = f2h(a[3]);
    o[4] = f2h(b[0]); o[5] = f2h(b[1]); o[6] = f2h(b[2]); o[7] = f2h(b[3]);
    *reinterpret_cast<u16x8*>(dst + doff + idx) = o;
}

// ---------------- QKV ----------------
__global__ __launch_bounds__(256, 2) void qkv_h_kernel(
    const u16* __restrict__ hb, const u16* __restrict__ Wqh, const u16* __restrict__ Wkh,
    const u16* __restrict__ Wvh, u16* __restrict__ qb, u16* __restrict__ kb, u16* __restrict__ vb) {
    __shared__ u16 As[128 * 64];
    __shared__ u16 Bs[128 * 64];
    int z = blockIdx.z;
    const u16* W = (z == 0) ? Wqh : (z == 1) ? Wkh : Wvh;
    u16* dst = (z == 0) ? qb : (z == 1) ? kb : vb;
    int m0 = blockIdx.y * 128, n0 = blockIdx.x * 128;
    f32x4 acc[4][4];
    f32x4 zf = {0.f, 0.f, 0.f, 0.f};
#pragma unroll
    for (int i = 0; i < 4; i++)
#pragma unroll
        for (int j = 0; j < 4; j++) acc[i][j] = zf;
    gemm128_core(hb, W, 1024, 0, 1024, m0, n0, As, Bs, acc);
    int lane = threadIdx.x & 63, w = threadIdx.x >> 6;
    int wm = (w >> 1) * 64, wn = (w & 1) * 64;
    int lrow = lane & 15, lg = lane >> 4;
#pragma unroll
    for (int i = 0; i < 4; i++)
#pragma unroll
        for (int j = 0; j < 4; j++)
#pragma unroll
            for (int r = 0; r < 4; r++) {
                int m = m0 + wm + i * 16 + lg * 4 + r;
                int n = n0 + wn + j * 16 + lrow;
                dst[(size_t)m * 1024 + n] = f2h(acc[i][j][r]);
            }
}

// ---------------- generic 128x128 GEMM, f16 out, optional K-split via grid.z ----------------
__global__ __launch_bounds__(256, 2) void gemm_h_kernel(
    const u16* __restrict__ A, const u16* __restrict__ B, u16* __restrict__ out,
    int ldk, int ksplit, int osplit, int N) {
    __shared__ u16 As[128 * 64];
    __shared__ u16 Bs[128 * 64];
    int z = blockIdx.z;
    int m0 = blockIdx.y * 128, n0 = blockIdx.x * 128;
    f32x4 acc[4][4];
    f32x4 zf = {0.f, 0.f, 0.f, 0.f};
#pragma unroll
    for (int i = 0; i < 4; i++)
#pragma unroll
        for (int j = 0; j < 4; j++) acc[i][j] = zf;
    gemm128_core(A, B, ldk, z * ksplit, (z + 1) * ksplit, m0, n0, As, Bs, acc);
    u16* o = out + (size_t)z * osplit;
    int lane = threadIdx.x & 63, w = threadIdx.x >> 6;
    int wm = (w >> 1) * 64, wn = (w & 1) * 64;
    int lrow = lane & 15, lg = lane >> 4;
#pragma unroll
    for (int i = 0; i < 4; i++)
#pragma unroll
        for (int j = 0; j < 4; j++)
#pragma unroll
            for (int r = 0; r < 4; r++) {
                int m = m0 + wm + i * 16 + lg * 4 + r;
                int n = n0 + wn + j * 16 + lrow;
                o[(size_t)m * N + n] = f2h(acc[i][j][r]);
            }
}

// ---------------- RoPE + L2 norm + sqk scale, f16 in-place ----------------
__global__ void qkprep_kernel(u16* __restrict__ qb, u16* __restrict__ kb,
                              const float* __restrict__ sqk) {
    u16* buf = blockIdx.z ? kb : qb;
    int pair = blockIdx.x * 4 + (threadIdx.x >> 6);  // (m,h) pair
    int m = pair >> 4, hh = pair & 15;
    int tt = m & 1023;  // t = m % T
    int d = threadIdx.x & 63;
    size_t off = (size_t)m * 1024 + hh * 64 + d;
    float x = h2f(buf[off]);
    float xn = __shfl_xor(x, 1);
    int j = (d & 1) ? ((d - 1) >> 1) : (32 + (d >> 1));
    float dv = exp2f(-(float)(j >> 1) * 0.41524101186092029f);  // log2(10000)/32
    float ang = (float)tt * dv;
    float e = (j & 1) ? cosf(ang) : sinf(ang);
    float xr = (d & 1) ? (xn * e) : (-xn * e);
    float ss = xr * xr;
#pragma unroll
    for (int o = 1; o < 64; o <<= 1) ss += __shfl_xor(ss, o);
    float sc = rsqrtf(ss) * sqk[hh * 64 + d] * 32.0f;
    buf[off] = f2h(xr * sc);
}

// ---------------- flash attention, split-KV x4, gate folded into softmax ----------------
// Round-8-validated structure: Vt LDS double-buffer (explicit bufsel), register K/V
// prefetch one owned-tile ahead, ONE barrier per tile, branch-free softmax:
// p = exp(s - m) * rcp(1 + exp(st*(thr-s))); m = max(s) - softplus(st*(thr - max s)).
__global__ __launch_bounds__(128) void attn_kernel(
    const u16* __restrict__ qb, const u16* __restrict__ kb, const u16* __restrict__ vb,
    const float* __restrict__ thr_c, const float* __restrict__ stp,
    u16* __restrict__ yph, f32x2* __restrict__ mden) {
    const int T = 1024, C = 1024;
    int qt = 31 - (blockIdx.x >> 2);  // heavy-first
    int c = blockIdx.x & 3;           // kv chunk (stride-4 tiles)
    int bh = blockIdx.y;
    int b = bh >> 4, hh = bh & 15;
    int q0 = qt * 32;
    int nkt = (q0 >> 6) + 1;
    __shared__ u16 Vt[2][64 * LDSS];  // double-buffered transposed V
    __shared__ u16 Ps[32 * LDSS];     // P[q_local][kv] (wave-private rows)
    int t = threadIdx.x;
    int lane = t & 63, w = t >> 6;
    int lrow = lane & 15, lg = lane >> 4, lk = lg * 8;
    int kvp = t & 31, db = t >> 5;    // V-stage lane mapping

    const u16* qrowp = qb + (size_t)(b * T + q0 + w * 16 + lrow) * C + hh * 64;
    f16x8 qfr[2];
    qfr[0] = *reinterpret_cast<const f16x8*>(qrowp + lk);
    qfr[1] = *reinterpret_cast<const f16x8*>(qrowp + 32 + lk);

    float thr = thr_c[hh], st = stp[hh];
    float stthr = st * thr;
    float mrun = -1e30f, den = 0.f;
    f32x4 yacc[4];
    f32x4 zf = {0.f, 0.f, 0.f, 0.f};
#pragma unroll
    for (int i = 0; i < 4; i++) yacc[i] = zf;
    int qg = q0 + w * 16 + lrow;

    f16x8 kpre[8];   // prefetched K fragments
    u16x4 vr[8];     // prefetched V rows (2 kv rows x 16 d)
    const u16* kbase0 = kb + (size_t)(b * T + lrow) * C + hh * 64 + lk;
    const u16* vbase0 = vb + (size_t)(b * T + 2 * kvp) * C + hh * 64 + db * 16;

    if (c < nkt) {  // prologue prefetch of tile c
        const u16* kbase = kbase0 + (size_t)(c << 6) * C;
        const u16* vsrc = vbase0 + (size_t)(c << 6) * C;
#pragma unroll
        for (int ks = 0; ks < 2; ks++)
#pragma unroll
            for (int f = 0; f < 4; f++)
                kpre[ks * 4 + f] = *reinterpret_cast<const f16x8*>(kbase + (size_t)(f * 16) * C + ks * 32);
#pragma unroll
        for (int dd = 0; dd < 4; dd++) {
            vr[dd * 2] = *reinterpret_cast<const u16x4*>(vsrc + dd * 4);
            vr[dd * 2 + 1] = *reinterpret_cast<const u16x4*>(vsrc + C + dd * 4);
        }
    }

    int bufsel = 0;
    for (int kt = c; kt < nkt; kt += 4) {
        int kv0 = kt << 6;
        u16* VB = Vt[bufsel];
        bufsel ^= 1;  // explicit alternation (stride-4 safe)
#pragma unroll
        for (int dd = 0; dd < 4; dd++)
#pragma unroll
            for (int e = 0; e < 4; e++) {
                u32 v = (u32)vr[dd * 2][e] | ((u32)vr[dd * 2 + 1][e] << 16);
                *reinterpret_cast<u32*>(&VB[(db * 16 + dd * 4 + e) * LDSS + 2 * kvp]) = v;
            }
        f32x4 sacc[4];
#pragma unroll
        for (int f = 0; f < 4; f++) sacc[f] = zf;
#pragma unroll
        for (int ks = 0; ks < 2; ks++)
#pragma unroll
            for (int f = 0; f < 4; f++)
                sacc[f] = mfma16(kpre[ks * 4 + f], qfr[ks], sacc[f]);

        if (kt + 4 < nkt) {
            const u16* kbase = kbase0 + (size_t)((kt + 4) << 6) * C;
            const u16* vsrc = vbase0 + (size_t)((kt + 4) << 6) * C;
#pragma unroll
            for (int ks = 0; ks < 2; ks++)
#pragma unroll
                for (int f = 0; f < 4; f++)
                    kpre[ks * 4 + f] = *reinterpret_cast<const f16x8*>(kbase + (size_t)(f * 16) * C + ks * 32);
#pragma unroll
            for (int dd = 0; dd < 4; dd++) {
                vr[dd * 2] = *reinterpret_cast<const u16x4*>(vsrc + dd * 4);
                vr[dd * 2 + 1] = *reinterpret_cast<const u16x4*>(vsrc + C + dd * 4);
            }
        }

        float svv[16];
        float tmax = -1e30f;
        bool last = (kt == nkt - 1);
#pragma unroll
        for (int f = 0; f < 4; f++)
#pragma unroll
            for (int r = 0; r < 4; r++) {
                float s = sacc[f][r] * 8.0f;  // * sqrt(D)
                if (last) {
                    int kvg = kv0 + f * 16 + lg * 4 + r;
                    if (kvg > qg) s = -1e30f;
                }
                svv[f * 4 + r] = s;
                tmax = fmaxf(tmax, s);
            }
        tmax = fmaxf(tmax, __shfl_xor(tmax, 16));
        tmax = fmaxf(tmax, __shfl_xor(tmax, 32));
        float zM = stthr - st * tmax;
        float spM = tmax - __logf(1.0f + __expf(zM));
        float mnew = fmaxf(mrun, spM);
        float alpha = __expf(mrun - mnew);
        float tden = 0.f;
        u16 pu[16];
#pragma unroll
        for (int i = 0; i < 16; i++) {
            float s = svv[i];
            float e2 = __expf(s - mnew);
            float eg = __expf(stthr - st * s);
            float p = e2 * __builtin_amdgcn_rcpf(1.0f + eg);
            u16 ph = f2h(p);
            pu[i] = ph;
            tden += h2f(ph);  // denominator from quantized P: rounding cancels
        }
        tden += __shfl_xor(tden, 16);
        tden += __shfl_xor(tden, 32);
        den = den * alpha + tden;
        mrun = mnew;

#pragma unroll
        for (int f = 0; f < 4; f++) {
            u16x4 u = {pu[f * 4 + 0], pu[f * 4 + 1], pu[f * 4 + 2], pu[f * 4 + 3]};
            *reinterpret_cast<u16x4*>(&Ps[(w * 16 + lrow) * LDSS + f * 16 + lg * 4]) = u;
        }
        float a4[4];
#pragma unroll
        for (int r = 0; r < 4; r++) a4[r] = __shfl(alpha, lg * 4 + r);
#pragma unroll
        for (int nf = 0; nf < 4; nf++)
#pragma unroll
            for (int r = 0; r < 4; r++) yacc[nf][r] *= a4[r];

        __syncthreads();  // VB staged; single barrier per tile (dbuf removes WAR hazard)

#pragma unroll
        for (int ks = 0; ks < 2; ks++) {
            f16x8 pf = *reinterpret_cast<f16x8*>(&Ps[(w * 16 + lrow) * LDSS + ks * 32 + lk]);
#pragma unroll
            for (int nf = 0; nf < 4; nf++) {
                f16x8 vf = *reinterpret_cast<f16x8*>(&VB[(nf * 16 + lrow) * LDSS + ks * 32 + lk]);
                yacc[nf] = mfma16(pf, vf, yacc[nf]);
            }
        }
    }
    u16* ypc = yph + (size_t)c * 2097152;
#pragma unroll
    for (int nf = 0; nf < 4; nf++)
#pragma unroll
        for (int r = 0; r < 4; r++) {
            int qrow = q0 + w * 16 + lg * 4 + r;
            ypc[(size_t)(b * T + qrow) * C + hh * 64 + nf * 16 + lrow] = f2h(yacc[nf][r]);
        }
    if (lg == 0) {
        f32x2 md;
        md[0] = mrun; md[1] = den;
        mden[((size_t)c * 32 + bh) * 1024 + (q0 + w * 16 + lrow)] = md;
    }
}

// ---------------- merge 4 split-KV partials -> normalized f16 y ----------------
__global__ void attn_merge_kernel(const u16* __restrict__ yph, const f32x2* __restrict__ mden,
                                  u16* __restrict__ y) {
    int row = blockIdx.x;  // b*T + t
    int b = row >> 10, tr = row & 1023;
    int t = threadIdx.x;
#pragma unroll
    for (int i = 0; i < 4; i++) {
        int idx = t + 256 * i;
        int hh = idx >> 6;
        float m[4], d[4];
        float M = -1e30f;
#pragma unroll
        for (int p = 0; p < 4; p++) {
            f32x2 md = mden[((size_t)p * 32 + b * 16 + hh) * 1024 + tr];
            m[p] = md[0]; d[p] = md[1];
            M = fmaxf(M, m[p]);
        }
        size_t off = (size_t)row * 1024 + idx;
        float dn = 0.f, acc = 0.f;
#pragma unroll
        for (int p = 0; p < 4; p++) {
            float wp = __expf(m[p] - M);
            dn += d[p] * wp;
            acc += h2f(yph[off + (size_t)p * 2097152]) * wp;
        }
        y[off] = f2h(acc / dn);
    }
}

// ---------------- FC (u and v halves) + SiLU gate fused, 128x128 tile ----------------
__global__ __launch_bounds__(256, 2) void fc_silu_kernel(
    const u16* __restrict__ h1h, const u16* __restrict__ Wfch,
    const float* __restrict__ suv, u16* __restrict__ xmlp) {
    __shared__ u16 As[128 * 64];
    __shared__ u16 Bu[128 * 64];
    __shared__ u16 Bv[128 * 64];
    int m0 = blockIdx.y * 128, n0 = blockIdx.x * 128;
    f32x4 au[4][4], av[4][4];
    f32x4 zf = {0.f, 0.f, 0.f, 0.f};
#pragma unroll
    for (int i = 0; i < 4; i++)
#pragma unroll
        for (int j = 0; j < 4; j++) { au[i][j] = zf; av[i][j] = zf; }
    int lane = threadIdx.x & 63, w = threadIdx.x >> 6;
    int wm = (w >> 1) * 64, wn = (w & 1) * 64;
    int lrow = lane & 15, lg = lane >> 4;
    for (int k0 = 0; k0 < 1024; k0 += 64) {
        __syncthreads();
        stage128(h1h, m0, 1024, k0, As);
        stage128(Wfch, n0, 1024, k0, Bu);
        stage128(Wfch, 4096 + n0, 1024, k0, Bv);
        __syncthreads();
#pragma unroll
        for (int ks = 0; ks < 2; ks++) {
            f16x8 af[4], bu[4], bv[4];
#pragma unroll
            for (int i = 0; i < 4; i++) {
                af[i] = *reinterpret_cast<f16x8*>(&As[(wm + i * 16 + lrow) * 64 + ks * 32 + lg * 8]);
                bu[i] = *reinterpret_cast<f16x8*>(&Bu[(wn + i * 16 + lrow) * 64 + ks * 32 + lg * 8]);
                bv[i] = *reinterpret_cast<f16x8*>(&Bv[(wn + i * 16 + lrow) * 64 + ks * 32 + lg * 8]);
            }
#pragma unroll
            for (int i = 0; i < 4; i++)
#pragma unroll
                for (int j = 0; j < 4; j++) {
                    au[i][j] = mfma16(af[i], bu[j], au[i][j]);
                    av[i][j] = mfma16(af[i], bv[j], av[i][j]);
                }
        }
    }
#pragma unroll
    for (int i = 0; i < 4; i++)
#pragma unroll
        for (int j = 0; j < 4; j++) {
            int n = n0 + wn + j * 16 + lrow;
            float su = suv[n] * 32.0f;
            float sv = suv[4096 + n] * 32.0f;
#pragma unroll
            for (int r = 0; r < 4; r++) {
                int m = m0 + wm + i * 16 + lg * 4 + r;
                float uu = au[i][j][r] * su;
                float vv = av[i][j][r] * sv;
                float sig = 1.0f / (1.0f + __expf(-vv));
                xmlp[(size_t)m * 4096 + n] = f2h(uu * vv * sig);
            }
        }
}

// ---------------- justnorm residual-lerp-justnorm; delta = sum of f16 parts ----------------
__global__ void normres_kernel(const float* __restrict__ base, const u16* __restrict__ dparts,
                               int nparts, int pstride, const float* __restrict__ alpha,
                               float* __restrict__ outf, u16* __restrict__ outh) {
    int row = blockIdx.x;
    int t = threadIdx.x;
    const float* pb = base + (size_t)row * 1024;
    float xb[4], xd[4];
    float ssb = 0.f, ssd = 0.f;
#pragma unroll
    for (int i = 0; i < 4; i++) {
        size_t off = (size_t)row * 1024 + t + 256 * i;
        xb[i] = pb[t + 256 * i];
        float d = 0.f;
        for (int p = 0; p < nparts; p++) d += h2f(dparts[off + (size_t)p * pstride]);
        xd[i] = d;
        ssb += xb[i] * xb[i];
        ssd += xd[i] * xd[i];
    }
#pragma unroll
    for (int o = 1; o < 64; o <<= 1) { ssb += __shfl_xor(ssb, o); ssd += __shfl_xor(ssd, o); }
    __shared__ float red[8];
    int w = t >> 6;
    if ((t & 63) == 0) { red[w * 2] = ssb; red[w * 2 + 1] = ssd; }
    __syncthreads();
    ssb = red[0] + red[2] + red[4] + red[6];
    ssd = red[1] + red[3] + red[5] + red[7];
    float rb = rsqrtf(ssb), rd = rsqrtf(ssd);
    float c[4];
    float ssc = 0.f;
#pragma unroll
    for (int i = 0; i < 4; i++) {
        float a = xb[i] * rb;
        float bb = xd[i] * rd;
        float lr = fabsf(alpha[t + 256 * i] * 1.6f);  // 0.05/0.03125
        float cv = a + lr * (bb - a);
        c[i] = cv;
        ssc += cv * cv;
    }
#pragma unroll
    for (int o = 1; o < 64; o <<= 1) ssc += __shfl_xor(ssc, o);
    __syncthreads();
    if ((t & 63) == 0) red[w] = ssc;
    __syncthreads();
    ssc = red[0] + red[1] + red[2] + red[3];
    float rc = rsqrtf(ssc);
#pragma unroll
    for (int i = 0; i < 4; i++) {
        float v = c[i] * rc;
        size_t off = (size_t)row * 1024 + t + 256 * i;
        outf[off] = v;
        if (outh) outh[off] = f2h(v);
    }
}

extern "C" void kernel_launch(void* const* d_in, const int* in_sizes, int n_in,
                              void* d_out, int out_size, void* d_ws, size_t ws_size,
                              hipStream_t stream) {
    const float* h = (const float*)d_in[0];
    const float* Wq = (const float*)d_in[1];
    const float* Wk = (const float*)d_in[2];
    const float* Wv = (const float*)d_in[3];
    const float* Wo = (const float*)d_in[4];
    const float* Wfc = (const float*)d_in[5];
    const float* Wproj = (const float*)d_in[6];
    const float* sqk = (const float*)d_in[7];
    const float* suv = (const float*)d_in[8];
    const float* attn_alpha = (const float*)d_in[9];
    const float* mlp_alpha = (const float*)d_in[10];
    const float* thr_c = (const float*)d_in[11];
    const float* stp = (const float*)d_in[12];

    char* ws = (char*)d_ws;
    u16* f16heap = (u16*)ws;
    u16* hb     = f16heap + 0;         // 2048x1024       ( 0..4MB)
    u16* Wqh    = f16heap + 2097152;   // 1024x1024       ( 4..6MB)
    u16* Wkh    = f16heap + 3145728;   //                 ( 6..8MB)
    u16* Wvh    = f16heap + 4194304;   //                 ( 8..10MB)
    u16* Woh    = f16heap + 5242880;   //                 (10..12MB)
    u16* Wprojh = f16heap + 6291456;   // 1024x4096       (12..20MB)
    u16* Wfch   = f16heap + 10485760;  // 8192x1024       (20..36MB)
    u16* partsP = Wfch;                // proj partials 4x(2048x1024), after Wfc dead
    u16* qb   = (u16*)(ws + (size_t)36 * MB);
    u16* kb   = (u16*)(ws + (size_t)40 * MB);
    u16* vb   = (u16*)(ws + (size_t)44 * MB);
    u16* y    = (u16*)(ws + (size_t)48 * MB);     // merged attn out (48..52)
    u16* yph  = (u16*)(ws + (size_t)52 * MB);     // 4 x 4MB f16 attn partials (52..68)
    f32x2* mden = (f32x2*)(ws + (size_t)68 * MB); // 1MB (68..69)
    u16* hattP = (u16*)(ws + (size_t)52 * MB);    // Wo partials 4x4MB (52..68; yph dead post-merge)
    float* h1 = (float*)(ws + (size_t)36 * MB);   // 36..44 (qb/kb dead post-attn)
    u16* h1h  = (u16*)(ws + (size_t)44 * MB);     // 44..48 (vb dead post-attn)
    u16* xmlp = (u16*)(ws + (size_t)52 * MB);     // 52..68 (hattP dead post-normres1)
    float* out = (float*)d_out;

    cvt_kernel<<<9216, 256, 0, stream>>>(h, Wq, Wk, Wv, Wo, Wfc, Wproj, f16heap);
    qkv_h_kernel<<<dim3(8, 16, 3), 256, 0, stream>>>(hb, Wqh, Wkh, Wvh, qb, kb, vb);
    qkprep_kernel<<<dim3(8192, 1, 2), 256, 0, stream>>>(qb, kb, sqk);
    attn_kernel<<<dim3(128, 32), 128, 0, stream>>>(qb, kb, vb, thr_c, stp, yph, mden);
    attn_merge_kernel<<<2048, 256, 0, stream>>>(yph, mden, y);
    gemm_h_kernel<<<dim3(8, 16, 4), 256, 0, stream>>>(y, Woh, hattP, 1024, 256, 2097152, 1024);
    normres_kernel<<<2048, 256, 0, stream>>>(h, hattP, 4, 2097152, attn_alpha, h1, h1h);
    fc_silu_kernel<<<dim3(32, 16), 256, 0, stream>>>(h1h, Wfch, suv, xmlp);
    gemm_h_kernel<<<dim3(8, 16, 4), 256, 0, stream>>>(xmlp, Wprojh, partsP, 4096, 1024, 2097152, 1024);
    normres_kernel<<<2048, 256, 0, stream>>>(h1, partsP, 4, 2097152, mlp_alpha, out, (u16*)nullptr);
}